// Round 3
// baseline (3296.594 us; speedup 1.0000x reference)
//
#include <hip/hip_runtime.h>
#include <math.h>

#define B_N 64
#define T_N 3072
#define FIN 128
#define TP 1024      // conv output length
#define COUT 64
#define HID 256
#define G4 1024      // 4*HID
#define OUT_N 10
#define NCHUNK 24
#define CHUNK_T (T_N / NCHUNK)   // 128

// v4 LSTM layout: 256 threads/block, 1 wave/EU -> 512 unified regs/thread.
// Thread m owns hidden unit m: all 4 gate rows (i,f,g,o) of w_hh.
// Per gate row: 128 f16x2 dwords = 32 uint4 chunks over h.
//   23 chunks x 4 gates x 4 dw = 368 dwords AGPR-pinned via asm (cannot be
//     remat'd or spilled if budget holds: 368 + ~110 arch <= 512).
//   9 chunks in LDS: 9*4*256*16 B = 144 KB.
// v3 failure (confirmed by counters): at 512 thr / waves_per_eu(2,2) the
// budget is 256; 116 arch + 192 AGPR = 308 > 256 -> AGPRs spilled to
// scratch -> same L2-class traffic as v1/v2 remat plus copy overhead.
#define WREG 23
#define WLDS 9
#define NTH 256

typedef _Float16 h2_t __attribute__((ext_vector_type(2)));
typedef unsigned u32x4 __attribute__((ext_vector_type(4)));
typedef float    f32x4 __attribute__((ext_vector_type(4)));

#if defined(__has_builtin)
#if __has_builtin(__builtin_amdgcn_fdot2)
#define HAVE_FDOT2 1
#endif
#endif

__device__ __forceinline__ float fdot2(unsigned w, unsigned h, float acc) {
#ifdef HAVE_FDOT2
    return __builtin_amdgcn_fdot2(__builtin_bit_cast(h2_t, w),
                                  __builtin_bit_cast(h2_t, h), acc, false);
#else
    h2_t wv = __builtin_bit_cast(h2_t, w), hv = __builtin_bit_cast(h2_t, h);
    return acc + (float)wv.x * (float)hv.x + (float)wv.y * (float)hv.y;
#endif
}

__device__ __forceinline__ unsigned pack2(float a, float b) {
    unsigned la = (unsigned)__builtin_bit_cast(unsigned short, (_Float16)a);
    unsigned lb = (unsigned)__builtin_bit_cast(unsigned short, (_Float16)b);
    return la | (lb << 16);
}

// ---------------------------------------------------------------------------
// Pack w_hh to f16x2 chunk layout [chunk c][gate g][unit m] (uint4 granules)
// and build wihT[k][1024] fp32 (original col order) for x_gemm.
// grid 1024 (col), 128 thr (d = packed dword 0..127).
// ---------------------------------------------------------------------------
__global__ void pack_weights(const float* __restrict__ w_ih,
                             const float* __restrict__ w_hh,
                             unsigned* __restrict__ whhR,   // [23][4][256] uint4, flat dwords
                             unsigned* __restrict__ whhL,   // [9][4][256] uint4, flat dwords
                             float* __restrict__ wihT) {    // [64][1024]
    int col = blockIdx.x, d = threadIdx.x;
    int m = col & 255, g = col >> 8;     // unit, gate (0=i,1=f,2=g,3=o)
    const float* wr = w_hh + col * HID;
    unsigned p = pack2(wr[2 * d], wr[2 * d + 1]);
    int c = d >> 2, r = d & 3;
    if (c < WREG) whhR[(((c * 4 + g) * 256 + m)) * 4 + r] = p;
    else          whhL[((((c - WREG) * 4 + g) * 256 + m)) * 4 + r] = p;
    if (d < COUT) wihT[d * 1024 + col] = w_ih[col * COUT + d];
}

// conv weight permute: wc2[j][oc], j = kk*128+ic
__global__ void prep_conv_w(const float* __restrict__ conv_w, float* __restrict__ wc2) {
    int i = blockIdx.x * 256 + threadIdx.x;
    if (i < 24576) {
        int j = i >> 6, oc = i & 63;
        int kk = j >> 7, ic = j & 127;
        wc2[i] = conv_w[(oc * 128 + ic) * 3 + kk];
    }
}

// ---------------------------------------------------------------------------
// partial sum-of-squares over time (F.normalize along dim=1)
// ---------------------------------------------------------------------------
__global__ void norm_partial(const float* __restrict__ in, float* __restrict__ part) {
    int b = blockIdx.x, ch = blockIdx.y, f = threadIdx.x;
    const float* p = in + ((size_t)b * T_N + (size_t)ch * CHUNK_T) * FIN + f;
    float s0 = 0.f, s1 = 0.f, s2 = 0.f, s3 = 0.f;
#pragma unroll
    for (int r = 0; r < CHUNK_T; r += 4) {
        float v0 = p[(r + 0) * FIN];
        float v1 = p[(r + 1) * FIN];
        float v2 = p[(r + 2) * FIN];
        float v3 = p[(r + 3) * FIN];
        s0 += v0 * v0; s1 += v1 * v1; s2 += v2 * v2; s3 += v3 * v3;
    }
    part[(b * NCHUNK + ch) * FIN + f] = (s0 + s1) + (s2 + s3);
}

// ---------------------------------------------------------------------------
// normalize + conv1d(k=3,stride=3) + bias + relu  (stride==K -> GEMM)
// ---------------------------------------------------------------------------
__global__ __launch_bounds__(256) void conv_relu(
        const float* __restrict__ in, const float* __restrict__ part,
        const float* __restrict__ wc2, const float* __restrict__ cb,
        float* __restrict__ X) {
    __shared__ __align__(16) float xs[16 * 384];
    __shared__ __align__(16) float wsh[96 * 64];
    __shared__ float invn[FIN];

    int b = blockIdx.x, tile = blockIdx.y;
    int tid = threadIdx.x;

    if (tid < FIN) {
        float s = 0.f;
#pragma unroll
        for (int c = 0; c < NCHUNK; c++) s += part[(b * NCHUNK + c) * FIN + tid];
        invn[tid] = rsqrtf(fmaxf(s, 1e-24f));
    }
    __syncthreads();

    const float* ip = in + ((size_t)b * T_N + (size_t)tile * 48) * FIN;
    for (int i = tid; i < 6144; i += 256) xs[i] = ip[i] * invn[i & 127];

    int oc = tid & 63, tq = tid >> 6;
    float acc0 = 0.f, acc1 = 0.f, acc2 = 0.f, acc3 = 0.f;
    const float* xb = xs + tq * 4 * 384;

    for (int c = 0; c < 4; c++) {
        __syncthreads();
        for (int i = tid; i < 6144; i += 256) wsh[i] = wc2[c * 6144 + i];
        __syncthreads();
#pragma unroll 8
        for (int jj = 0; jj < 96; jj += 4) {
            int j = c * 96 + jj;
            float w0 = wsh[(jj + 0) * 64 + oc];
            float w1 = wsh[(jj + 1) * 64 + oc];
            float w2 = wsh[(jj + 2) * 64 + oc];
            float w3 = wsh[(jj + 3) * 64 + oc];
            float4 x0 = *(const float4*)(xb + j);
            float4 x1 = *(const float4*)(xb + 384 + j);
            float4 x2 = *(const float4*)(xb + 768 + j);
            float4 x3 = *(const float4*)(xb + 1152 + j);
            acc0 += w0 * x0.x + w1 * x0.y + w2 * x0.z + w3 * x0.w;
            acc1 += w0 * x1.x + w1 * x1.y + w2 * x1.z + w3 * x1.w;
            acc2 += w0 * x2.x + w1 * x2.y + w2 * x2.z + w3 * x2.w;
            acc3 += w0 * x3.x + w1 * x3.y + w2 * x3.z + w3 * x3.w;
        }
    }
    float bb = cb[oc];
    int tp0 = tile * 16 + tq * 4;
    size_t o = ((size_t)b * TP + tp0) * COUT + oc;
    X[o]       = fmaxf(acc0 + bb, 0.f);
    X[o + 64]  = fmaxf(acc1 + bb, 0.f);
    X[o + 128] = fmaxf(acc2 + bb, 0.f);
    X[o + 192] = fmaxf(acc3 + bb, 0.f);
}

// ---------------------------------------------------------------------------
// x-projection GEMM: gate[b,t,c] = X[b,t,:] @ w_ih[c,:] + b_ih[c] + b_hh[c],
// stored f16: dword (t*512 + m) = pack2(i,f) of unit m; dword (t*512+256+m)
// = pack2(g,o). All 4 gate columns of unit tid fused into ONE k-loop
// (x-tile read once, as aligned float4). grid (64 b, 64 t-tiles of 16).
// ---------------------------------------------------------------------------
__global__ __launch_bounds__(256) void x_gemm(
        const float* __restrict__ X, const float* __restrict__ wihT,
        const float* __restrict__ b_ih, const float* __restrict__ b_hh,
        _Float16* __restrict__ xg) {
    __shared__ __align__(16) float xs[64 * 20];   // [k][r], row stride 20
    int b = blockIdx.x, t0 = blockIdx.y * 16, tid = threadIdx.x;

    const float* Xp = X + ((size_t)b * TP + t0) * COUT;
    for (int i = tid; i < 1024; i += 256) {
        int r = i >> 6, k = i & 63;
        xs[k * 20 + r] = Xp[i];
    }
    __syncthreads();

    int cI = tid, cF = tid + 256, cG = tid + 512, cO = tid + 768;
    float bI = b_ih[cI] + b_hh[cI];
    float bF = b_ih[cF] + b_hh[cF];
    float bG = b_ih[cG] + b_hh[cG];
    float bO = b_ih[cO] + b_hh[cO];

    f32x4 aI[4], aF[4], aG[4], aO[4];
#pragma unroll
    for (int q = 0; q < 4; q++) {
        aI[q] = bI; aF[q] = bF; aG[q] = bG; aO[q] = bO;
    }

    for (int k = 0; k < 64; k++) {
        float wI = wihT[k * 1024 + cI];
        float wF = wihT[k * 1024 + cF];
        float wG = wihT[k * 1024 + cG];
        float wO = wihT[k * 1024 + cO];
        const f32x4* xv = (const f32x4*)(xs + k * 20);
#pragma unroll
        for (int q = 0; q < 4; q++) {
            f32x4 x4 = xv[q];
            aI[q] += wI * x4;
            aF[q] += wF * x4;
            aG[q] += wG * x4;
            aO[q] += wO * x4;
        }
    }

    unsigned* xgu = (unsigned*)xg;
    size_t base = ((size_t)b * TP + t0) * 512;
#pragma unroll
    for (int r = 0; r < 16; r++) {
        int q = r >> 2, e = r & 3;
        xgu[base + (size_t)r * 512 + tid]       = pack2(aI[q][e], aF[q][e]);
        xgu[base + (size_t)r * 512 + 256 + tid] = pack2(aG[q][e], aO[q][e]);
    }
}

// ---------------------------------------------------------------------------
// Persistent LSTM v4: 64 blocks x 256 threads, 1 block/CU, 1 wave/EU.
// Thread m = hidden unit m, computes all 4 gates; c in register; h via
// LDS ping-pong with uniform (broadcast) ds_read_b128; ONE barrier/step.
// ---------------------------------------------------------------------------
__device__ __forceinline__ float fsig(float x) {
    return 1.f / (1.f + __expf(-x));
}
__device__ __forceinline__ float ftanh(float x) {
    float xc = fminf(fmaxf(x, -15.f), 15.f);
    float e = __expf(2.f * xc);
    return (e - 1.f) / (e + 1.f);
}

#define SM_WL   0                 // 9*4*256*16 = 147456 B
#define SM_H    147456            // two 512 B h buffers (ping-pong)
#define SM_H32  148480            // 256 f32 final h
#define SM_SIZE 149504

#define REP23(M) M(0) M(1) M(2) M(3) M(4) M(5) M(6) M(7) M(8) M(9) M(10) M(11) \
                 M(12) M(13) M(14) M(15) M(16) M(17) M(18) M(19) M(20) M(21) M(22)
#define REP9(M)  M(0) M(1) M(2) M(3) M(4) M(5) M(6) M(7) M(8)

#define AGW(dst, src) asm volatile("v_accvgpr_write_b32 %0, %1" : "=a"(dst) : "v"(src));

#define DECLW(n)  unsigned wi##n##_0, wi##n##_1, wi##n##_2, wi##n##_3, \
                           wf##n##_0, wf##n##_1, wf##n##_2, wf##n##_3, \
                           wg##n##_0, wg##n##_1, wg##n##_2, wg##n##_3, \
                           wo##n##_0, wo##n##_1, wo##n##_2, wo##n##_3;

#define LOADW(n)  { \
    u32x4 t0 = whhR4[((n) * 4 + 0) * 256 + m]; \
    AGW(wi##n##_0, t0[0]) AGW(wi##n##_1, t0[1]) AGW(wi##n##_2, t0[2]) AGW(wi##n##_3, t0[3]) \
    u32x4 t1 = whhR4[((n) * 4 + 1) * 256 + m]; \
    AGW(wf##n##_0, t1[0]) AGW(wf##n##_1, t1[1]) AGW(wf##n##_2, t1[2]) AGW(wf##n##_3, t1[3]) \
    u32x4 t2 = whhR4[((n) * 4 + 2) * 256 + m]; \
    AGW(wg##n##_0, t2[0]) AGW(wg##n##_1, t2[1]) AGW(wg##n##_2, t2[2]) AGW(wg##n##_3, t2[3]) \
    u32x4 t3 = whhR4[((n) * 4 + 3) * 256 + m]; \
    AGW(wo##n##_0, t3[0]) AGW(wo##n##_1, t3[1]) AGW(wo##n##_2, t3[2]) AGW(wo##n##_3, t3[3]) }

// 4 AGPR->VGPR copies then 4 dots (dep distance >= 4 instrs)
#define DOTG(acc, w0n, w1n, w2n, w3n, H) { \
    unsigned W0, W1, W2, W3; \
    asm volatile("v_accvgpr_read_b32 %0, %1" : "=v"(W0) : "a"(w0n)); \
    asm volatile("v_accvgpr_read_b32 %0, %1" : "=v"(W1) : "a"(w1n)); \
    asm volatile("v_accvgpr_read_b32 %0, %1" : "=v"(W2) : "a"(w2n)); \
    asm volatile("v_accvgpr_read_b32 %0, %1" : "=v"(W3) : "a"(w3n)); \
    acc = fdot2(W0, H[0], acc); acc = fdot2(W1, H[1], acc); \
    acc = fdot2(W2, H[2], acc); acc = fdot2(W3, H[3], acc); }

#define DOTCH(n)  { u32x4 H = hs4[n]; \
    DOTG(a_i, wi##n##_0, wi##n##_1, wi##n##_2, wi##n##_3, H) \
    DOTG(a_f, wf##n##_0, wf##n##_1, wf##n##_2, wf##n##_3, H) \
    DOTG(a_g, wg##n##_0, wg##n##_1, wg##n##_2, wg##n##_3, H) \
    DOTG(a_o, wo##n##_0, wo##n##_1, wo##n##_2, wo##n##_3, H) }

#define DOTLDS(q) { u32x4 H = hs4[WREG + (q)]; \
    u32x4 Wi = wL[((q) * 4 + 0) * 256 + m]; \
    u32x4 Wf = wL[((q) * 4 + 1) * 256 + m]; \
    u32x4 Wg = wL[((q) * 4 + 2) * 256 + m]; \
    u32x4 Wo = wL[((q) * 4 + 3) * 256 + m]; \
    a_i = fdot2(Wi[0], H[0], a_i); a_i = fdot2(Wi[1], H[1], a_i); \
    a_i = fdot2(Wi[2], H[2], a_i); a_i = fdot2(Wi[3], H[3], a_i); \
    a_f = fdot2(Wf[0], H[0], a_f); a_f = fdot2(Wf[1], H[1], a_f); \
    a_f = fdot2(Wf[2], H[2], a_f); a_f = fdot2(Wf[3], H[3], a_f); \
    a_g = fdot2(Wg[0], H[0], a_g); a_g = fdot2(Wg[1], H[1], a_g); \
    a_g = fdot2(Wg[2], H[2], a_g); a_g = fdot2(Wg[3], H[3], a_g); \
    a_o = fdot2(Wo[0], H[0], a_o); a_o = fdot2(Wo[1], H[1], a_o); \
    a_o = fdot2(Wo[2], H[2], a_o); a_o = fdot2(Wo[3], H[3], a_o); }

__global__ __attribute__((amdgpu_flat_work_group_size(NTH, NTH),
                          amdgpu_waves_per_eu(1, 1)))
void lstm_kernel(
        const u32x4* __restrict__ whhR4, const u32x4* __restrict__ whhL4,
        const _Float16* __restrict__ xg,
        const float* __restrict__ hx0, const float* __restrict__ cx0,
        const float* __restrict__ lin_w, const float* __restrict__ lin_b,
        float* __restrict__ out) {
    extern __shared__ char smem[];
    u32x4*    wL    = (u32x4*)(smem + SM_WL);       // [9][4][256] uint4
    _Float16* hbuf  = (_Float16*)(smem + SM_H);     // 2 x 256 (ping-pong)
    float*    h32_s = (float*)(smem + SM_H32);      // 256

    const int b = blockIdx.x, m = threadIdx.x;      // m = hidden unit

    // AGPR-pinned w_hh chunks: 23 chunks x 4 gates x 4 dw = 368 AGPRs
    REP23(DECLW)
    REP23(LOADW)

    // stage LDS-resident chunks (9 x 4 x 256 uint4)
    for (int i = m; i < WLDS * 1024; i += NTH) wL[i] = whhL4[i];

    float c_reg = cx0[b * HID + m];
    hbuf[m] = (_Float16)hx0[b * HID + m];           // buffer 0 = h(0)

    const unsigned* Xgu = (const unsigned*)xg + (size_t)b * TP * 512;
    unsigned xif = Xgu[m], xgo = Xgu[256 + m];
    __syncthreads();

    for (int t = 0; t < TP; t++) {
        const u32x4* hs4 = (const u32x4*)(hbuf + (t & 1) * 256);

        // prefetch next step's x-projection (clamped; last iter unused)
        int tn = (t + 1 < TP) ? t + 1 : t;
        unsigned xifn = Xgu[(size_t)tn * 512 + m];
        unsigned xgon = Xgu[(size_t)tn * 512 + 256 + m];

        h2_t vif = __builtin_bit_cast(h2_t, xif);
        h2_t vgo = __builtin_bit_cast(h2_t, xgo);
        float a_i = (float)vif.x, a_f = (float)vif.y;   // bias folded in xg
        float a_g = (float)vgo.x, a_o = (float)vgo.y;

        REP23(DOTCH)
        REP9(DOTLDS)

        float si = fsig(a_i), sf = fsig(a_f);
        float tg = ftanh(a_g), so = fsig(a_o);
        c_reg = sf * c_reg + si * tg;
        float hh = so * ftanh(c_reg);
        hbuf[((t + 1) & 1) * 256 + m] = (_Float16)hh;
        if (t == TP - 1) h32_s[m] = hh;
        __syncthreads();
        xif = xifn; xgo = xgon;
    }

    // epilogue: out[b] = h @ lin_w.T + lin_b  (fp32 h)
    if (m < OUT_N) {
        float s = lin_b[m];
        const float* lw = lin_w + m * HID;
#pragma unroll 4
        for (int k = 0; k < HID; k++) s += h32_s[k] * lw[k];
        out[b * OUT_N + m] = s;
    }
}

// ---------------------------------------------------------------------------
extern "C" void kernel_launch(void* const* d_in, const int* in_sizes, int n_in,
                              void* d_out, int out_size, void* d_ws, size_t ws_size,
                              hipStream_t stream) {
    const float* input  = (const float*)d_in[0];
    // d_in[1] = r (unused)
    const float* hx0    = (const float*)d_in[2];
    const float* cx0    = (const float*)d_in[3];
    const float* conv_w = (const float*)d_in[4];
    const float* conv_b = (const float*)d_in[5];
    const float* w_ih   = (const float*)d_in[6];
    const float* b_ih   = (const float*)d_in[7];
    const float* w_hh   = (const float*)d_in[8];
    const float* b_hh   = (const float*)d_in[9];
    const float* lin_w  = (const float*)d_in[10];
    const float* lin_b  = (const float*)d_in[11];

    float* ws = (float*)d_ws;
    float*     part = ws;                      // 196608 floats
    float*     X    = part + 196608;           // 4194304 floats
    float*     wc2  = X + 4194304;             // 24576 floats
    float*     wihT = wc2 + 24576;             // 65536 floats
    unsigned*  whhR = (unsigned*)(wihT + 65536);  // 23*1024*4 dwords
    unsigned*  whhL = whhR + WREG * 1024 * 4;     // 9*1024*4 dwords
    _Float16*  xg   = (_Float16*)(whhL + WLDS * 1024 * 4);  // 64*1024*1024 halves

    (void)hipFuncSetAttribute((const void*)lstm_kernel,
                              hipFuncAttributeMaxDynamicSharedMemorySize, SM_SIZE);

    pack_weights<<<1024, 128, 0, stream>>>(w_ih, w_hh, whhR, whhL, wihT);
    prep_conv_w<<<96, 256, 0, stream>>>(conv_w, wc2);
    norm_partial<<<dim3(B_N, NCHUNK), FIN, 0, stream>>>(input, part);
    conv_relu<<<dim3(B_N, 64), 256, 0, stream>>>(input, part, wc2, conv_b, X);
    x_gemm<<<dim3(B_N, 64), 256, 0, stream>>>(X, wihT, b_ih, b_hh, xg);
    lstm_kernel<<<B_N, NTH, SM_SIZE, stream>>>(
        (const u32x4*)whhR, (const u32x4*)whhL, xg,
        hx0, cx0, lin_w, lin_b, (float*)d_out);
}